// Round 4
// baseline (2576.489 us; speedup 1.0000x reference)
//
#include <hip/hip_runtime.h>

// Entmax-1.5 loss, n=4096 rows x d=32000 fp32 logits -> scalar mean loss.
// Root-finding formulation (no sort): tau solves sum clip(x/2 - T, 0)^2 = 1,
// support always contained in {x > xmax - 2}.
//
// Round-4: kill register pressure in the streaming kernel (r3 post-mortem:
// register-resident row (v[32] + in-flight loads) at the 64-VGPR cap of
// launch_bounds(1024,8) -> spill/serialized loads -> collect ran ~2.4x off
// the 83us streaming roofline).
//  K1 entmax15_collect: NO resident row. Each wave streams its chunks with a
//     2-deep prefetch pipeline (~2 live float4s, ~30 VGPR), keeps a WAVE
//     RUNNING max, and ballot-compacts x > Mrun-2 (a safe SUPERSET of the
//     exact x > xmax-2 set, since Mrun <= xmax) into its own LDS segment
//     (mean ~233/wave, WCAP=512, overflow P~1e-15 -> s_bad -> K2 full-D
//     fallback). Then block max, then ALL waves prune LDS -> global segment
//     with the exact threshold y > c-1 (~445 cands). All waves exit together.
//  K2 entmax15_solve: one wave per row; 12 Newton iters + exact quadratic
//     (reference formula) + loss from the pruned segment (L2/L3-resident).
//  K3 reduce_partials: sum per-row losses.
// Monolithic fallback kept if ws is too small.

#define D          32000
#define NF4        8000      // D/4
#define REM4       832       // NF4 - 7*1024
#define BLK        1024
#define NWAVE      16
#define WCAP       512       // per-wave LDS collect capacity (mean ~233)
#define CAPF       4096      // per-row global candidate capacity (floats)
#define NEWTON_IT  12

__device__ __forceinline__ int lane_prefix(unsigned long long b) {
    return __builtin_amdgcn_mbcnt_hi((unsigned int)(b >> 32),
           __builtin_amdgcn_mbcnt_lo((unsigned int)b, 0u));
}

// ---------------- K1: stream + running-max collect + prune to global --------
__global__ __launch_bounds__(BLK, 8)
void entmax15_collect(const float* __restrict__ x,
                      float* __restrict__ maxs,
                      int*   __restrict__ cnts,
                      float* __restrict__ cand) {
    __shared__ float s_buf[NWAVE * WCAP];   // 32 KB: per-wave segments
    __shared__ float s_red[NWAVE];
    __shared__ float s_max;
    __shared__ int   s_cnt2;
    __shared__ int   s_bad;

    const int tid  = threadIdx.x;
    const int lane = tid & 63;
    const int wave = tid >> 6;
    const int r    = blockIdx.x;
    const float4* row4 = (const float4*)(x + (size_t)r * D);
    float* wseg = s_buf + wave * WCAP;

    if (tid == 0) { s_cnt2 = 0; s_bad = 0; }

    float Mx = -1e30f;   // wave running max of x (uniform after per-chunk reduce)
    int   wn = 0;        // wave-uniform count of pushed candidates

    auto process4 = [&](float4 t) {
        // tighten the wave max with this chunk first (still <= xmax: safe)
        float m4 = fmaxf(fmaxf(t.x, t.y), fmaxf(t.z, t.w));
#pragma unroll
        for (int off = 32; off > 0; off >>= 1) m4 = fmaxf(m4, __shfl_xor(m4, off));
        Mx = fmaxf(Mx, m4);
        const float thr = Mx - 2.0f;
#pragma unroll
        for (int c4 = 0; c4 < 4; ++c4) {
            float xv = (c4 == 0) ? t.x : (c4 == 1) ? t.y : (c4 == 2) ? t.z : t.w;
            bool cnd = (xv > thr);
            unsigned long long b = __ballot(cnd);
            if (b) {                              // wave-uniform branch
                if (cnd) {
                    int p = wn + lane_prefix(b);
                    if (p < WCAP) wseg[p] = 0.5f * xv;   // store y = x/2
                }
                wn += (int)__popcll(b);           // register counter, no atomics
            }
        }
    };

    // 2-deep prefetch pipeline: ~2 live float4s, no register blowup
    float4 cur = row4[tid];
#pragma unroll 1
    for (int i = 0; i < 7; ++i) {
        float4 nxt = cur;
        if (i < 6)            nxt = row4[tid + (i + 1) * 1024];
        else if (tid < REM4)  nxt = row4[tid + 7 * 1024];
        process4(cur);
        cur = nxt;
    }
    if (tid < REM4) process4(cur);    // remainder chunk: waves 0..12 exactly

    if (lane == 0) {
        s_red[wave] = Mx;
        if (wn > WCAP) s_bad = 1;     // racing same-value writes: fine
    }
    __syncthreads();
    if (tid < 64) {
        float mm = (lane < NWAVE) ? s_red[lane] : -1e30f;
#pragma unroll
        for (int off = 8; off > 0; off >>= 1) mm = fmaxf(mm, __shfl_xor(mm, off));
        if (lane == 0) s_max = mm;
    }
    __syncthreads();

    // prune own segment with the EXACT threshold y > c-1, write to global
    const float xmax = s_max;
    const float thrY = 0.5f * xmax - 1.0f;
    float* seg = cand + (size_t)r * CAPF;
    const int cw = (wn < WCAP) ? wn : WCAP;
    for (int j0 = 0; j0 < cw; j0 += 64) {
        int   j = j0 + lane;
        float y = (j < cw) ? wseg[j] : -1e30f;
        bool  cnd = (y > thrY);
        unsigned long long b = __ballot(cnd);
        if (b) {
            int base = 0;
            if (lane == 0) base = atomicAdd(&s_cnt2, (int)__popcll(b));
            base = __shfl(base, 0);   // few atomics per wave total
            if (cnd) {
                int p = base + lane_prefix(b);
                if (p < CAPF) seg[p] = y;
            }
        }
    }
    __syncthreads();
    if (tid == 0) {
        cnts[r] = s_bad ? (CAPF + 1) : s_cnt2;   // sentinel -> K2 full-D path
        maxs[r] = xmax;
    }
}

// ---------------- K2: one wave per row, solve + loss ----------------
__global__ __launch_bounds__(64)
void entmax15_solve(const float* __restrict__ x,
                    const int* __restrict__ tgt,
                    const float* __restrict__ maxs,
                    const int*   __restrict__ cnts,
                    const float* __restrict__ cand,
                    float* __restrict__ partial) {
    const int lane = threadIdx.x;
    const int r    = blockIdx.x;
    const float* row = x + (size_t)r * D;
    const float* seg = cand + (size_t)r * CAPF;

    const int   cnt  = cnts[r];
    const float xmax = maxs[r];
    const bool  ovf  = cnt > CAPF;    // correctness fallback only
    const int   nn   = ovf ? 0 : cnt;

    const float c    = 0.5f * xmax;
    const float Tcap = c - 0.0055f;   // tau <= c - 1/sqrt(d) always
    float T = c - 1.0f;

    // Newton from below: f(T) = sum u^2 - 1, u = max(y-T,0)
    for (int it = 0; it < NEWTON_IT; ++it) {
        float S1 = 0.f, S2 = 0.f;
        for (int j = lane; j < nn; j += 64) {
            float u = fmaxf(seg[j] - T, 0.f);
            S1 += u; S2 = fmaf(u, u, S2);
        }
        if (ovf)
            for (int j = lane; j < D; j += 64) {
                float u = fmaxf(0.5f * row[j] - T, 0.f);
                S1 += u; S2 = fmaf(u, u, S2);
            }
#pragma unroll
        for (int off = 32; off > 0; off >>= 1) {
            S1 += __shfl_xor(S1, off);
            S2 += __shfl_xor(S2, off);
        }
        T = fminf(T + 0.5f * (S2 - 1.0f) / S1, Tcap);
    }

    // exact quadratic solve over stabilized support (reference formula)
    {
        float k = 0.f, B = 0.f, A = 0.f;
        for (int j = lane; j < nn; j += 64) {
            float y = seg[j];
            if (y > T) { k += 1.f; B += y; A = fmaf(y, y, A); }
        }
        if (ovf)
            for (int j = lane; j < D; j += 64) {
                float y = 0.5f * row[j];
                if (y > T) { k += 1.f; B += y; A = fmaf(y, y, A); }
            }
#pragma unroll
        for (int off = 32; off > 0; off >>= 1) {
            k += __shfl_xor(k, off);
            B += __shfl_xor(B, off);
            A += __shfl_xor(A, off);
        }
        float mean  = B / k;
        float delta = fmaxf(fmaf(mean, mean, -(A - 1.f) / k), 0.f);
        T = fminf(mean - sqrtf(delta), Tcap);
    }

    // loss: S15 = sum u^3, Spx = sum u^2 * 2y  (u = y - T > 0)
    float S15 = 0.f, Spx = 0.f;
    for (int j = lane; j < nn; j += 64) {
        float y = seg[j];
        float u = y - T;
        if (u > 0.f) { float p = u * u; S15 = fmaf(p, u, S15); Spx = fmaf(p, 2.f * y, Spx); }
    }
    if (ovf)
        for (int j = lane; j < D; j += 64) {
            float xv = row[j];
            float u  = 0.5f * xv - T;
            if (u > 0.f) { float p = u * u; S15 = fmaf(p, u, S15); Spx = fmaf(p, xv, Spx); }
        }
#pragma unroll
    for (int off = 32; off > 0; off >>= 1) {
        S15 += __shfl_xor(S15, off);
        Spx += __shfl_xor(Spx, off);
    }

    if (lane == 0) {
        float xt   = row[tgt[r]];
        partial[r] = (1.f - S15) * (4.f / 3.f) + Spx - xt;
    }
}

// ---------------- K3: reduce ----------------
__global__ __launch_bounds__(1024)
void reduce_partials(const float* __restrict__ p, float* __restrict__ out,
                     int n, float inv_n) {
    __shared__ float s_red[16];
    const int tid = threadIdx.x, lane = tid & 63, wave = tid >> 6;
    float v = 0.f;
    for (int i = tid; i < n; i += 1024) v += p[i];
#pragma unroll
    for (int off = 32; off > 0; off >>= 1) v += __shfl_xor(v, off);
    if (lane == 0) s_red[wave] = v;
    __syncthreads();
    if (tid < 64) {
        float t = (lane < 16) ? s_red[lane] : 0.f;
#pragma unroll
        for (int off = 8; off > 0; off >>= 1) t += __shfl_xor(t, off);
        if (lane == 0) out[0] = t * inv_n;
    }
}

// ---------------- fallback: monolithic (ws too small) ----------------
__global__ __launch_bounds__(BLK, 8)
void entmax15_rows(const float* __restrict__ x,
                   const int* __restrict__ tgt,
                   float* __restrict__ out,
                   float inv_n) {
    __shared__ float s_buf[CAPF];
    __shared__ float s_red[16];
    __shared__ float s_max;
    __shared__ int   s_cnt;

    const int tid  = threadIdx.x;
    const int lane = tid & 63;
    const int wave = tid >> 6;
    const int r    = blockIdx.x;
    const float*  row  = x + (size_t)r * D;
    const float4* row4 = (const float4*)row;

    if (tid == 0) s_cnt = 0;

    float v[32];
#pragma unroll
    for (int i = 0; i < 7; ++i) {
        float4 t = row4[tid + i * 1024];
        v[4*i+0] = t.x; v[4*i+1] = t.y; v[4*i+2] = t.z; v[4*i+3] = t.w;
    }
    if (tid < REM4) {
        float4 t = row4[tid + 7 * 1024];
        v[28] = t.x; v[29] = t.y; v[30] = t.z; v[31] = t.w;
    } else {
        v[28] = v[29] = v[30] = v[31] = -1e30f;
    }

    float m = -1e30f;
#pragma unroll
    for (int i = 0; i < 32; ++i) m = fmaxf(m, v[i]);
#pragma unroll
    for (int off = 32; off > 0; off >>= 1) m = fmaxf(m, __shfl_xor(m, off));
    if (lane == 0) s_red[wave] = m;
    __syncthreads();
    if (tid < 64) {
        float mm = (lane < 16) ? s_red[lane] : -1e30f;
#pragma unroll
        for (int off = 8; off > 0; off >>= 1) mm = fmaxf(mm, __shfl_xor(mm, off));
        if (lane == 0) s_max = mm;
    }
    __syncthreads();

    const float xmax = s_max;
    const float thr  = xmax - 2.0f;

#pragma unroll
    for (int i = 0; i < 32; ++i) {
        bool cnd = (v[i] > thr);
        unsigned long long b = __ballot(cnd);
        if (b) {
            int base = 0;
            if (lane == 0) base = atomicAdd(&s_cnt, (int)__popcll(b));
            base = __shfl(base, 0);
            if (cnd) {
                int p = base + lane_prefix(b);
                if (p < CAPF) s_buf[p] = 0.5f * v[i];
            }
        }
    }
    __syncthreads();

    const int  cnt = s_cnt;
    const bool ovf = cnt > CAPF;
    if (tid >= 64) return;

    const float c    = 0.5f * xmax;
    const float Tcap = c - 0.0055f;
    const int   nn   = ovf ? 0 : cnt;
    float T = c - 1.0f;

    for (int it = 0; it < NEWTON_IT; ++it) {
        float S1 = 0.f, S2 = 0.f;
        for (int j = lane; j < nn; j += 64) {
            float u = fmaxf(s_buf[j] - T, 0.f);
            S1 += u; S2 = fmaf(u, u, S2);
        }
        if (ovf)
            for (int j = lane; j < D; j += 64) {
                float u = fmaxf(0.5f * row[j] - T, 0.f);
                S1 += u; S2 = fmaf(u, u, S2);
            }
#pragma unroll
        for (int off = 32; off > 0; off >>= 1) {
            S1 += __shfl_xor(S1, off);
            S2 += __shfl_xor(S2, off);
        }
        T = fminf(T + 0.5f * (S2 - 1.0f) / S1, Tcap);
    }
    {
        float k = 0.f, B = 0.f, A = 0.f;
        for (int j = lane; j < nn; j += 64) {
            float y = s_buf[j];
            if (y > T) { k += 1.f; B += y; A = fmaf(y, y, A); }
        }
        if (ovf)
            for (int j = lane; j < D; j += 64) {
                float y = 0.5f * row[j];
                if (y > T) { k += 1.f; B += y; A = fmaf(y, y, A); }
            }
#pragma unroll
        for (int off = 32; off > 0; off >>= 1) {
            k += __shfl_xor(k, off);
            B += __shfl_xor(B, off);
            A += __shfl_xor(A, off);
        }
        float mean  = B / k;
        float delta = fmaxf(fmaf(mean, mean, -(A - 1.f) / k), 0.f);
        T = fminf(mean - sqrtf(delta), Tcap);
    }
    float S15 = 0.f, Spx = 0.f;
    for (int j = lane; j < nn; j += 64) {
        float y = s_buf[j];
        float u = y - T;
        if (u > 0.f) { float p = u * u; S15 = fmaf(p, u, S15); Spx = fmaf(p, 2.f * y, Spx); }
    }
    if (ovf)
        for (int j = lane; j < D; j += 64) {
            float xv = row[j];
            float u  = 0.5f * xv - T;
            if (u > 0.f) { float p = u * u; S15 = fmaf(p, u, S15); Spx = fmaf(p, xv, Spx); }
        }
#pragma unroll
    for (int off = 32; off > 0; off >>= 1) {
        S15 += __shfl_xor(S15, off);
        Spx += __shfl_xor(Spx, off);
    }
    if (lane == 0) {
        float xt   = row[tgt[r]];
        float loss = (1.f - S15) * (4.f / 3.f) + Spx - xt;
        atomicAdd(out, loss * inv_n);
    }
}

extern "C" void kernel_launch(void* const* d_in, const int* in_sizes, int n_in,
                              void* d_out, int out_size, void* d_ws, size_t ws_size,
                              hipStream_t stream) {
    const float* xin = (const float*)d_in[0];
    const int*   tgt = (const int*)d_in[1];
    float*       out = (float*)d_out;
    const int n = in_sizes[0] / D;           // 4096 rows
    const float inv_n = 1.0f / (float)n;

    // ws layout (floats): [0,n) partial | [n,2n) maxs | [2n,3n) cnts(int)
    //                     | [coff, coff + n*CAPF) candidates
    const size_t coff = ((size_t)3 * n + 63) & ~(size_t)63;
    const size_t need = (coff + (size_t)n * CAPF) * sizeof(float);

    if (d_ws && ws_size >= need) {
        float* wsf     = (float*)d_ws;
        float* partial = wsf;
        float* maxs    = wsf + n;
        int*   cnts    = (int*)(wsf + 2 * (size_t)n);
        float* cand    = wsf + coff;

        entmax15_collect<<<n, BLK, 0, stream>>>(xin, maxs, cnts, cand);
        entmax15_solve<<<n, 64, 0, stream>>>(xin, tgt, maxs, cnts, cand, partial);
        reduce_partials<<<1, 1024, 0, stream>>>(partial, out, n, inv_n);
    } else {
        hipMemsetAsync(out, 0, sizeof(float), stream);
        entmax15_rows<<<n, BLK, 0, stream>>>(xin, tgt, out, inv_n);
    }
}

// Round 5
// 732.138 us; speedup vs baseline: 3.5191x; 3.5191x over previous
//
#include <hip/hip_runtime.h>

// Entmax-1.5 loss, n=4096 rows x d=32000 fp32 logits -> scalar mean loss.
// Root-finding formulation (no sort): tau solves sum clip(x/2 - T, 0)^2 = 1,
// support always contained in {x > xmax - 2}.
//
// Round-5 (post-mortem r4: WCAP=512 sized at the MEAN of a Gumbel-tailed
// count -> 8% of rows overflowed -> full-D fallback = 1910us solve kernel).
//  K1 entmax15_collect: streaming, no resident row.
//   - WCAP=1024 (overflow needs wave-max < 2.41, P ~ 7.5e-8/wave)
//   - in-wave compaction valve: if a chunk might overflow, refilter the
//     wave's own LDS segment with the current exact threshold (wave-private,
//     rare, ~1us). s_bad then needs TRUE count > 768: P ~ exp(-20).
//   - chunk i pushes use the max over chunks 0..i-1 (lag-1 threshold, still
//     a safe superset since Mrun <= xmax); the 6-shfl chunk-max reduction
//     overlaps the pushes instead of gating them.
//   - then block max, prune LDS -> global seg with exact y > c-1.
//  K2 entmax15_solve: one wave/row, Newton + exact quadratic + loss from seg.
//  K3 reduce_partials. Monolithic fallback if ws too small.

#define D          32000
#define NF4        8000      // D/4
#define REM4       832       // NF4 - 7*1024
#define BLK        1024
#define NWAVE      16
#define WCAP       1024      // per-wave LDS collect capacity (mean ~376)
#define CAPF       4096      // per-row global candidate capacity (floats)
#define NEWTON_IT  12

__device__ __forceinline__ int lane_prefix(unsigned long long b) {
    return __builtin_amdgcn_mbcnt_hi((unsigned int)(b >> 32),
           __builtin_amdgcn_mbcnt_lo((unsigned int)b, 0u));
}

// ---------------- K1: stream + lag-1 running-max collect + prune ------------
__global__ __launch_bounds__(BLK, 4)
void entmax15_collect(const float* __restrict__ x,
                      float* __restrict__ maxs,
                      int*   __restrict__ cnts,
                      float* __restrict__ cand) {
    __shared__ float s_buf[NWAVE * WCAP];   // 64 KB: per-wave segments
    __shared__ float s_red[NWAVE];
    __shared__ float s_max;
    __shared__ int   s_cnt2;
    __shared__ int   s_bad;

    const int tid  = threadIdx.x;
    const int lane = tid & 63;
    const int wave = tid >> 6;
    const int r    = blockIdx.x;
    const float4* row4 = (const float4*)(x + (size_t)r * D);
    float* wseg = s_buf + wave * WCAP;

    if (tid == 0) { s_cnt2 = 0; s_bad = 0; }

    float Mx = -1e30f;   // wave max over chunks processed so far (uniform)
    int   wn = 0;        // wave-uniform count of entries in wseg

    // wave-private in-place refilter of wseg with current threshold (rare)
    auto compact = [&]() {
        const float ythr = 0.5f * (Mx - 2.0f);
        int nw = 0;
        for (int j0 = 0; j0 < wn; j0 += 64) {
            int   j = j0 + lane;
            float y = (j < wn) ? wseg[j] : -1e30f;
            bool  keep = (y > ythr);
            unsigned long long b = __ballot(keep);
            int pos = nw + lane_prefix(b);
            if (keep) wseg[pos] = y;     // pos < j0+64: never clobbers unread
            nw += (int)__popcll(b);
        }
        wn = nw;
    };

    // push one float4-chunk; thr from chunks BEFORE this one (lag-1, safe)
    auto process4 = [&](float4 t, bool first) {
        float m4 = fmaxf(fmaxf(t.x, t.y), fmaxf(t.z, t.w));
#pragma unroll
        for (int off = 32; off > 0; off >>= 1) m4 = fmaxf(m4, __shfl_xor(m4, off));
        if (first) Mx = m4;              // chunk 0: must wait for its own max
        if (wn + 256 > WCAP) {           // capacity valve (P ~ 4e-5 per wave)
            compact();
            if (wn + 256 > WCAP && lane == 0) s_bad = 1;  // true count huge
        }
        const float thr = Mx - 2.0f;
#pragma unroll
        for (int c4 = 0; c4 < 4; ++c4) {
            float xv = (c4 == 0) ? t.x : (c4 == 1) ? t.y : (c4 == 2) ? t.z : t.w;
            bool cnd = (xv > thr);
            unsigned long long b = __ballot(cnd);
            if (b) {                              // wave-uniform branch
                if (cnd) {
                    int p = wn + lane_prefix(b);
                    if (p < WCAP) wseg[p] = 0.5f * xv;   // store y = x/2
                }
                wn += (int)__popcll(b);
            }
        }
        Mx = fmaxf(Mx, m4);              // absorb this chunk for the next one
    };

    // 2-deep prefetch pipeline; ~2 live float4s
    float4 cur = row4[tid];
#pragma unroll 1
    for (int i = 0; i < 7; ++i) {
        float4 nxt = cur;
        if (i < 6)            nxt = row4[tid + (i + 1) * 1024];
        else if (tid < REM4)  nxt = row4[tid + 7 * 1024];
        process4(cur, i == 0);
        cur = nxt;
    }
    if (tid < REM4) process4(cur, false);   // remainder: waves 0..12 exactly

    if (lane == 0) s_red[wave] = Mx;
    __syncthreads();
    if (tid < 64) {
        float mm = (lane < NWAVE) ? s_red[lane] : -1e30f;
#pragma unroll
        for (int off = 8; off > 0; off >>= 1) mm = fmaxf(mm, __shfl_xor(mm, off));
        if (lane == 0) s_max = mm;
    }
    __syncthreads();

    // prune own segment with the EXACT threshold y > c-1, write to global
    const float xmax = s_max;
    const float thrY = 0.5f * xmax - 1.0f;
    float* seg = cand + (size_t)r * CAPF;
    const int cw = (wn < WCAP) ? wn : WCAP;
    for (int j0 = 0; j0 < cw; j0 += 64) {
        int   j = j0 + lane;
        float y = (j < cw) ? wseg[j] : -1e30f;
        bool  cnd = (y > thrY);
        unsigned long long b = __ballot(cnd);
        if (b) {
            int base = 0;
            if (lane == 0) base = atomicAdd(&s_cnt2, (int)__popcll(b));
            base = __shfl(base, 0);
            if (cnd) {
                int p = base + lane_prefix(b);
                if (p < CAPF) seg[p] = y;
            }
        }
    }
    __syncthreads();
    if (tid == 0) {
        cnts[r] = (s_bad || s_cnt2 > CAPF) ? (CAPF + 1) : s_cnt2;
        maxs[r] = xmax;
    }
}

// ---------------- K2: one wave per row, solve + loss ----------------
__global__ __launch_bounds__(64)
void entmax15_solve(const float* __restrict__ x,
                    const int* __restrict__ tgt,
                    const float* __restrict__ maxs,
                    const int*   __restrict__ cnts,
                    const float* __restrict__ cand,
                    float* __restrict__ partial) {
    const int lane = threadIdx.x;
    const int r    = blockIdx.x;
    const float* row = x + (size_t)r * D;
    const float* seg = cand + (size_t)r * CAPF;

    const int   cnt  = cnts[r];
    const float xmax = maxs[r];
    const bool  ovf  = cnt > CAPF;    // correctness net only (P ~ exp(-20))
    const int   nn   = ovf ? 0 : cnt;

    const float c    = 0.5f * xmax;
    const float Tcap = c - 0.0055f;   // tau <= c - 1/sqrt(d) always
    float T = c - 1.0f;

    // Newton from below: f(T) = sum u^2 - 1, u = max(y-T,0)
    for (int it = 0; it < NEWTON_IT; ++it) {
        float S1 = 0.f, S2 = 0.f;
        for (int j = lane; j < nn; j += 64) {
            float u = fmaxf(seg[j] - T, 0.f);
            S1 += u; S2 = fmaf(u, u, S2);
        }
        if (ovf)
            for (int j = lane; j < D; j += 64) {
                float u = fmaxf(0.5f * row[j] - T, 0.f);
                S1 += u; S2 = fmaf(u, u, S2);
            }
#pragma unroll
        for (int off = 32; off > 0; off >>= 1) {
            S1 += __shfl_xor(S1, off);
            S2 += __shfl_xor(S2, off);
        }
        T = fminf(T + 0.5f * (S2 - 1.0f) / S1, Tcap);
    }

    // exact quadratic solve over stabilized support (reference formula)
    {
        float k = 0.f, B = 0.f, A = 0.f;
        for (int j = lane; j < nn; j += 64) {
            float y = seg[j];
            if (y > T) { k += 1.f; B += y; A = fmaf(y, y, A); }
        }
        if (ovf)
            for (int j = lane; j < D; j += 64) {
                float y = 0.5f * row[j];
                if (y > T) { k += 1.f; B += y; A = fmaf(y, y, A); }
            }
#pragma unroll
        for (int off = 32; off > 0; off >>= 1) {
            k += __shfl_xor(k, off);
            B += __shfl_xor(B, off);
            A += __shfl_xor(A, off);
        }
        float mean  = B / k;
        float delta = fmaxf(fmaf(mean, mean, -(A - 1.f) / k), 0.f);
        T = fminf(mean - sqrtf(delta), Tcap);
    }

    // loss: S15 = sum u^3, Spx = sum u^2 * 2y  (u = y - T > 0)
    float S15 = 0.f, Spx = 0.f;
    for (int j = lane; j < nn; j += 64) {
        float y = seg[j];
        float u = y - T;
        if (u > 0.f) { float p = u * u; S15 = fmaf(p, u, S15); Spx = fmaf(p, 2.f * y, Spx); }
    }
    if (ovf)
        for (int j = lane; j < D; j += 64) {
            float xv = row[j];
            float u  = 0.5f * xv - T;
            if (u > 0.f) { float p = u * u; S15 = fmaf(p, u, S15); Spx = fmaf(p, xv, Spx); }
        }
#pragma unroll
    for (int off = 32; off > 0; off >>= 1) {
        S15 += __shfl_xor(S15, off);
        Spx += __shfl_xor(Spx, off);
    }

    if (lane == 0) {
        float xt   = row[tgt[r]];
        partial[r] = (1.f - S15) * (4.f / 3.f) + Spx - xt;
    }
}

// ---------------- K3: reduce ----------------
__global__ __launch_bounds__(1024)
void reduce_partials(const float* __restrict__ p, float* __restrict__ out,
                     int n, float inv_n) {
    __shared__ float s_red[16];
    const int tid = threadIdx.x, lane = tid & 63, wave = tid >> 6;
    float v = 0.f;
    for (int i = tid; i < n; i += 1024) v += p[i];
#pragma unroll
    for (int off = 32; off > 0; off >>= 1) v += __shfl_xor(v, off);
    if (lane == 0) s_red[wave] = v;
    __syncthreads();
    if (tid < 64) {
        float t = (lane < 16) ? s_red[lane] : 0.f;
#pragma unroll
        for (int off = 8; off > 0; off >>= 1) t += __shfl_xor(t, off);
        if (lane == 0) out[0] = t * inv_n;
    }
}

// ---------------- fallback: monolithic (ws too small) ----------------
__global__ __launch_bounds__(BLK, 8)
void entmax15_rows(const float* __restrict__ x,
                   const int* __restrict__ tgt,
                   float* __restrict__ out,
                   float inv_n) {
    __shared__ float s_buf[CAPF];
    __shared__ float s_red[16];
    __shared__ float s_max;
    __shared__ int   s_cnt;

    const int tid  = threadIdx.x;
    const int lane = tid & 63;
    const int wave = tid >> 6;
    const int r    = blockIdx.x;
    const float*  row  = x + (size_t)r * D;
    const float4* row4 = (const float4*)row;

    if (tid == 0) s_cnt = 0;

    float v[32];
#pragma unroll
    for (int i = 0; i < 7; ++i) {
        float4 t = row4[tid + i * 1024];
        v[4*i+0] = t.x; v[4*i+1] = t.y; v[4*i+2] = t.z; v[4*i+3] = t.w;
    }
    if (tid < REM4) {
        float4 t = row4[tid + 7 * 1024];
        v[28] = t.x; v[29] = t.y; v[30] = t.z; v[31] = t.w;
    } else {
        v[28] = v[29] = v[30] = v[31] = -1e30f;
    }

    float m = -1e30f;
#pragma unroll
    for (int i = 0; i < 32; ++i) m = fmaxf(m, v[i]);
#pragma unroll
    for (int off = 32; off > 0; off >>= 1) m = fmaxf(m, __shfl_xor(m, off));
    if (lane == 0) s_red[wave] = m;
    __syncthreads();
    if (tid < 64) {
        float mm = (lane < 16) ? s_red[lane] : -1e30f;
#pragma unroll
        for (int off = 8; off > 0; off >>= 1) mm = fmaxf(mm, __shfl_xor(mm, off));
        if (lane == 0) s_max = mm;
    }
    __syncthreads();

    const float xmax = s_max;
    const float thr  = xmax - 2.0f;

#pragma unroll
    for (int i = 0; i < 32; ++i) {
        bool cnd = (v[i] > thr);
        unsigned long long b = __ballot(cnd);
        if (b) {
            int base = 0;
            if (lane == 0) base = atomicAdd(&s_cnt, (int)__popcll(b));
            base = __shfl(base, 0);
            if (cnd) {
                int p = base + lane_prefix(b);
                if (p < CAPF) s_buf[p] = 0.5f * v[i];
            }
        }
    }
    __syncthreads();

    const int  cnt = s_cnt;
    const bool ovf = cnt > CAPF;
    if (tid >= 64) return;

    const float c    = 0.5f * xmax;
    const float Tcap = c - 0.0055f;
    const int   nn   = ovf ? 0 : cnt;
    float T = c - 1.0f;

    for (int it = 0; it < NEWTON_IT; ++it) {
        float S1 = 0.f, S2 = 0.f;
        for (int j = lane; j < nn; j += 64) {
            float u = fmaxf(s_buf[j] - T, 0.f);
            S1 += u; S2 = fmaf(u, u, S2);
        }
        if (ovf)
            for (int j = lane; j < D; j += 64) {
                float u = fmaxf(0.5f * row[j] - T, 0.f);
                S1 += u; S2 = fmaf(u, u, S2);
            }
#pragma unroll
        for (int off = 32; off > 0; off >>= 1) {
            S1 += __shfl_xor(S1, off);
            S2 += __shfl_xor(S2, off);
        }
        T = fminf(T + 0.5f * (S2 - 1.0f) / S1, Tcap);
    }
    {
        float k = 0.f, B = 0.f, A = 0.f;
        for (int j = lane; j < nn; j += 64) {
            float y = s_buf[j];
            if (y > T) { k += 1.f; B += y; A = fmaf(y, y, A); }
        }
        if (ovf)
            for (int j = lane; j < D; j += 64) {
                float y = 0.5f * row[j];
                if (y > T) { k += 1.f; B += y; A = fmaf(y, y, A); }
            }
#pragma unroll
        for (int off = 32; off > 0; off >>= 1) {
            k += __shfl_xor(k, off);
            B += __shfl_xor(B, off);
            A += __shfl_xor(A, off);
        }
        float mean  = B / k;
        float delta = fmaxf(fmaf(mean, mean, -(A - 1.f) / k), 0.f);
        T = fminf(mean - sqrtf(delta), Tcap);
    }
    float S15 = 0.f, Spx = 0.f;
    for (int j = lane; j < nn; j += 64) {
        float y = s_buf[j];
        float u = y - T;
        if (u > 0.f) { float p = u * u; S15 = fmaf(p, u, S15); Spx = fmaf(p, 2.f * y, Spx); }
    }
    if (ovf)
        for (int j = lane; j < D; j += 64) {
            float xv = row[j];
            float u  = 0.5f * xv - T;
            if (u > 0.f) { float p = u * u; S15 = fmaf(p, u, S15); Spx = fmaf(p, xv, Spx); }
        }
#pragma unroll
    for (int off = 32; off > 0; off >>= 1) {
        S15 += __shfl_xor(S15, off);
        Spx += __shfl_xor(Spx, off);
    }
    if (lane == 0) {
        float xt   = row[tgt[r]];
        float loss = (1.f - S15) * (4.f / 3.f) + Spx - xt;
        atomicAdd(out, loss * inv_n);
    }
}

extern "C" void kernel_launch(void* const* d_in, const int* in_sizes, int n_in,
                              void* d_out, int out_size, void* d_ws, size_t ws_size,
                              hipStream_t stream) {
    const float* xin = (const float*)d_in[0];
    const int*   tgt = (const int*)d_in[1];
    float*       out = (float*)d_out;
    const int n = in_sizes[0] / D;           // 4096 rows
    const float inv_n = 1.0f / (float)n;

    // ws layout (floats): [0,n) partial | [n,2n) maxs | [2n,3n) cnts(int)
    //                     | [coff, coff + n*CAPF) candidates
    const size_t coff = ((size_t)3 * n + 63) & ~(size_t)63;
    const size_t need = (coff + (size_t)n * CAPF) * sizeof(float);

    if (d_ws && ws_size >= need) {
        float* wsf     = (float*)d_ws;
        float* partial = wsf;
        float* maxs    = wsf + n;
        int*   cnts    = (int*)(wsf + 2 * (size_t)n);
        float* cand    = wsf + coff;

        entmax15_collect<<<n, BLK, 0, stream>>>(xin, maxs, cnts, cand);
        entmax15_solve<<<n, 64, 0, stream>>>(xin, tgt, maxs, cnts, cand, partial);
        reduce_partials<<<1, 1024, 0, stream>>>(partial, out, n, inv_n);
    } else {
        hipMemsetAsync(out, 0, sizeof(float), stream);
        entmax15_rows<<<n, BLK, 0, stream>>>(xin, tgt, out, inv_n);
    }
}

// Round 7
// 731.387 us; speedup vs baseline: 3.5227x; 1.0010x over previous
//
#include <hip/hip_runtime.h>

// Entmax-1.5 loss, n=4096 rows x d=32000 fp32 logits -> scalar mean loss.
// Root-finding formulation (no sort): tau solves sum clip(x/2 - T, 0)^2 = 1,
// support always contained in {x > xmax - 2}.
//
// Round-7 = round-6 design with the compile error fixed (single-arg fmaxf
// in the phase-B max; now a named vmax4 helper). Theory unchanged:
// prior collects sustained ~1 outstanding load/wave (~2.2 TB/s). Two-half
// phase split -> 4 float4 loads in flight/wave at <64 VGPR, phase-A
// compaction overlaps phase-B load latency.
//  K1 entmax15_collect:
//    half A (chunks 0-3) -> regs -> block max M1
//    issue half B (chunks 4-7); compact half A vs M1-2 (superset of exact
//      set since M1 <= xmax; extras filtered by y > T in the solve)
//    block max M; compact half B vs the exact M-2
//    coalesced copy LDS -> per-row global segment (~300 floats)
//    CAPF=4096 overflow: needs row-max < 3.05, P ~ 1.5e-8/row ->
//    sentinel -> K2 full-D fallback (correctness net only).
//  K2 entmax15_solve: one wave/row, 12 Newton + exact quadratic (reference
//    formula) + loss from the segment (L2/L3-resident).
//  K3 reduce_partials. Monolithic fallback if ws too small.

#define D          32000
#define NF4        8000      // D/4
#define REM4       832       // NF4 - 7*1024
#define BLK        1024
#define CAPF       4096      // per-row candidate capacity (16 KB LDS)
#define NEWTON_IT  12

__device__ __forceinline__ int lane_prefix(unsigned long long b) {
    return __builtin_amdgcn_mbcnt_hi((unsigned int)(b >> 32),
           __builtin_amdgcn_mbcnt_lo((unsigned int)b, 0u));
}

__device__ __forceinline__ float vmax4(float4 t) {
    return fmaxf(fmaxf(t.x, t.y), fmaxf(t.z, t.w));
}

// ---------------- K1: two-phase streaming collect ----------------
__global__ __launch_bounds__(BLK, 8)
void entmax15_collect(const float* __restrict__ x,
                      float* __restrict__ maxs,
                      int*   __restrict__ cnts,
                      float* __restrict__ cand) {
    __shared__ float s_buf[CAPF];     // 16 KB candidates (y = x/2)
    __shared__ float s_red[16];
    __shared__ float s_m1;
    __shared__ float s_m2;
    __shared__ int   s_cnt;

    const int tid  = threadIdx.x;
    const int lane = tid & 63;
    const int wave = tid >> 6;
    const int r    = blockIdx.x;
    const float4* row4 = (const float4*)(x + (size_t)r * D);

    if (tid == 0) s_cnt = 0;

    // ---- phase A: issue chunks 0..3 (4 loads in flight) ----
    float4 f0 = row4[tid];
    float4 f1 = row4[tid + 1024];
    float4 f2 = row4[tid + 2048];
    float4 f3 = row4[tid + 3072];

    float m = fmaxf(fmaxf(vmax4(f0), vmax4(f1)), fmaxf(vmax4(f2), vmax4(f3)));
#pragma unroll
    for (int off = 32; off > 0; off >>= 1) m = fmaxf(m, __shfl_xor(m, off));
    if (lane == 0) s_red[wave] = m;
    __syncthreads();
    if (tid < 64) {
        float mm = (lane < 16) ? s_red[lane] : -1e30f;
#pragma unroll
        for (int off = 8; off > 0; off >>= 1) mm = fmaxf(mm, __shfl_xor(mm, off));
        if (lane == 0) s_m1 = mm;
    }
    __syncthreads();
    const float M1 = s_m1;

    // ---- issue chunks 4..7 (4 loads in flight) ----
    float4 g0 = row4[tid + 4096];
    float4 g1 = row4[tid + 5120];
    float4 g2 = row4[tid + 6144];
    float4 g3;
    if (tid < REM4) g3 = row4[tid + 7168];
    else            g3 = make_float4(-1e30f, -1e30f, -1e30f, -1e30f);

    // ---- compact phase A vs M1-2 while phase-B loads fly ----
    auto push = [&](float xv, float thr) {
        bool cnd = (xv > thr);
        unsigned long long b = __ballot(cnd);
        if (b) {                                 // wave-uniform branch
            int base = 0;
            if (lane == 0) base = atomicAdd(&s_cnt, (int)__popcll(b));
            base = __shfl(base, 0);
            if (cnd) {
                int p = base + lane_prefix(b);
                if (p < CAPF) s_buf[p] = 0.5f * xv;   // store y = x/2
            }
        }
    };
    {
        const float thrA = M1 - 2.0f;   // M1 <= xmax: safe superset
        push(f0.x, thrA); push(f0.y, thrA); push(f0.z, thrA); push(f0.w, thrA);
        push(f1.x, thrA); push(f1.y, thrA); push(f1.z, thrA); push(f1.w, thrA);
        push(f2.x, thrA); push(f2.y, thrA); push(f2.z, thrA); push(f2.w, thrA);
        push(f3.x, thrA); push(f3.y, thrA); push(f3.z, thrA); push(f3.w, thrA);
    }

    // ---- block max of phase B (waits the g-loads; compaction overlapped) ----
    float m2 = fmaxf(fmaxf(vmax4(g0), vmax4(g1)), fmaxf(vmax4(g2), vmax4(g3)));
#pragma unroll
    for (int off = 32; off > 0; off >>= 1) m2 = fmaxf(m2, __shfl_xor(m2, off));
    __syncthreads();                  // all waves done with phase-A s_red use
    if (lane == 0) s_red[wave] = m2;
    __syncthreads();
    if (tid < 64) {
        float mm = (lane < 16) ? s_red[lane] : -1e30f;
#pragma unroll
        for (int off = 8; off > 0; off >>= 1) mm = fmaxf(mm, __shfl_xor(mm, off));
        if (lane == 0) s_m2 = mm;
    }
    __syncthreads();
    const float M = fmaxf(M1, s_m2);  // exact row max

    // ---- compact phase B vs the exact M-2 ----
    {
        const float thrB = M - 2.0f;
        push(g0.x, thrB); push(g0.y, thrB); push(g0.z, thrB); push(g0.w, thrB);
        push(g1.x, thrB); push(g1.y, thrB); push(g1.z, thrB); push(g1.w, thrB);
        push(g2.x, thrB); push(g2.y, thrB); push(g2.z, thrB); push(g2.w, thrB);
        push(g3.x, thrB); push(g3.y, thrB); push(g3.z, thrB); push(g3.w, thrB);
    }
    __syncthreads();

    // ---- coalesced copy LDS -> global segment ----
    const int cnt = s_cnt;
    const int cc  = (cnt < CAPF) ? cnt : CAPF;
    float* seg = cand + (size_t)r * CAPF;
    for (int j = tid; j < cc; j += BLK) seg[j] = s_buf[j];
    if (tid == 0) {
        cnts[r] = (cnt > CAPF) ? (CAPF + 1) : cnt;   // sentinel -> full-D path
        maxs[r] = M;
    }
}

// ---------------- K2: one wave per row, solve + loss ----------------
__global__ __launch_bounds__(64)
void entmax15_solve(const float* __restrict__ x,
                    const int* __restrict__ tgt,
                    const float* __restrict__ maxs,
                    const int*   __restrict__ cnts,
                    const float* __restrict__ cand,
                    float* __restrict__ partial) {
    const int lane = threadIdx.x;
    const int r    = blockIdx.x;
    const float* row = x + (size_t)r * D;
    const float* seg = cand + (size_t)r * CAPF;

    const int   cnt  = cnts[r];
    const float xmax = maxs[r];
    const bool  ovf  = cnt > CAPF;    // correctness net only
    const int   nn   = ovf ? 0 : cnt;

    const float c    = 0.5f * xmax;
    const float Tcap = c - 0.0055f;   // tau <= c - 1/sqrt(d) always
    float T = c - 1.0f;

    // Newton from below: f(T) = sum u^2 - 1, u = max(y-T,0)
    for (int it = 0; it < NEWTON_IT; ++it) {
        float S1 = 0.f, S2 = 0.f;
        for (int j = lane; j < nn; j += 64) {
            float u = fmaxf(seg[j] - T, 0.f);
            S1 += u; S2 = fmaf(u, u, S2);
        }
        if (ovf)
            for (int j = lane; j < D; j += 64) {
                float u = fmaxf(0.5f * row[j] - T, 0.f);
                S1 += u; S2 = fmaf(u, u, S2);
            }
#pragma unroll
        for (int off = 32; off > 0; off >>= 1) {
            S1 += __shfl_xor(S1, off);
            S2 += __shfl_xor(S2, off);
        }
        T = fminf(T + 0.5f * (S2 - 1.0f) / S1, Tcap);
    }

    // exact quadratic solve over stabilized support (reference formula)
    {
        float k = 0.f, B = 0.f, A = 0.f;
        for (int j = lane; j < nn; j += 64) {
            float y = seg[j];
            if (y > T) { k += 1.f; B += y; A = fmaf(y, y, A); }
        }
        if (ovf)
            for (int j = lane; j < D; j += 64) {
                float y = 0.5f * row[j];
                if (y > T) { k += 1.f; B += y; A = fmaf(y, y, A); }
            }
#pragma unroll
        for (int off = 32; off > 0; off >>= 1) {
            k += __shfl_xor(k, off);
            B += __shfl_xor(B, off);
            A += __shfl_xor(A, off);
        }
        float mean  = B / k;
        float delta = fmaxf(fmaf(mean, mean, -(A - 1.f) / k), 0.f);
        T = fminf(mean - sqrtf(delta), Tcap);
    }

    // loss: S15 = sum u^3, Spx = sum u^2 * 2y  (u = y - T > 0)
    float S15 = 0.f, Spx = 0.f;
    for (int j = lane; j < nn; j += 64) {
        float y = seg[j];
        float u = y - T;
        if (u > 0.f) { float p = u * u; S15 = fmaf(p, u, S15); Spx = fmaf(p, 2.f * y, Spx); }
    }
    if (ovf)
        for (int j = lane; j < D; j += 64) {
            float xv = row[j];
            float u  = 0.5f * xv - T;
            if (u > 0.f) { float p = u * u; S15 = fmaf(p, u, S15); Spx = fmaf(p, xv, Spx); }
        }
#pragma unroll
    for (int off = 32; off > 0; off >>= 1) {
        S15 += __shfl_xor(S15, off);
        Spx += __shfl_xor(Spx, off);
    }

    if (lane == 0) {
        float xt   = row[tgt[r]];
        partial[r] = (1.f - S15) * (4.f / 3.f) + Spx - xt;
    }
}

// ---------------- K3: reduce ----------------
__global__ __launch_bounds__(1024)
void reduce_partials(const float* __restrict__ p, float* __restrict__ out,
                     int n, float inv_n) {
    __shared__ float s_red[16];
    const int tid = threadIdx.x, lane = tid & 63, wave = tid >> 6;
    float v = 0.f;
    for (int i = tid; i < n; i += 1024) v += p[i];
#pragma unroll
    for (int off = 32; off > 0; off >>= 1) v += __shfl_xor(v, off);
    if (lane == 0) s_red[wave] = v;
    __syncthreads();
    if (tid < 64) {
        float t = (lane < 16) ? s_red[lane] : 0.f;
#pragma unroll
        for (int off = 8; off > 0; off >>= 1) t += __shfl_xor(t, off);
        if (lane == 0) out[0] = t * inv_n;
    }
}

// ---------------- fallback: monolithic (ws too small) ----------------
__global__ __launch_bounds__(BLK, 8)
void entmax15_rows(const float* __restrict__ x,
                   const int* __restrict__ tgt,
                   float* __restrict__ out,
                   float inv_n) {
    __shared__ float s_buf[CAPF];
    __shared__ float s_red[16];
    __shared__ float s_max;
    __shared__ int   s_cnt;

    const int tid  = threadIdx.x;
    const int lane = tid & 63;
    const int wave = tid >> 6;
    const int r    = blockIdx.x;
    const float*  row  = x + (size_t)r * D;
    const float4* row4 = (const float4*)row;

    if (tid == 0) s_cnt = 0;

    float v[32];
#pragma unroll
    for (int i = 0; i < 7; ++i) {
        float4 t = row4[tid + i * 1024];
        v[4*i+0] = t.x; v[4*i+1] = t.y; v[4*i+2] = t.z; v[4*i+3] = t.w;
    }
    if (tid < REM4) {
        float4 t = row4[tid + 7 * 1024];
        v[28] = t.x; v[29] = t.y; v[30] = t.z; v[31] = t.w;
    } else {
        v[28] = v[29] = v[30] = v[31] = -1e30f;
    }

    float m = -1e30f;
#pragma unroll
    for (int i = 0; i < 32; ++i) m = fmaxf(m, v[i]);
#pragma unroll
    for (int off = 32; off > 0; off >>= 1) m = fmaxf(m, __shfl_xor(m, off));
    if (lane == 0) s_red[wave] = m;
    __syncthreads();
    if (tid < 64) {
        float mm = (lane < 16) ? s_red[lane] : -1e30f;
#pragma unroll
        for (int off = 8; off > 0; off >>= 1) mm = fmaxf(mm, __shfl_xor(mm, off));
        if (lane == 0) s_max = mm;
    }
    __syncthreads();

    const float xmax = s_max;
    const float thr  = xmax - 2.0f;

#pragma unroll
    for (int i = 0; i < 32; ++i) {
        bool cnd = (v[i] > thr);
        unsigned long long b = __ballot(cnd);
        if (b) {
            int base = 0;
            if (lane == 0) base = atomicAdd(&s_cnt, (int)__popcll(b));
            base = __shfl(base, 0);
            if (cnd) {
                int p = base + lane_prefix(b);
                if (p < CAPF) s_buf[p] = 0.5f * v[i];
            }
        }
    }
    __syncthreads();

    const int  cnt = s_cnt;
    const bool ovf = cnt > CAPF;
    if (tid >= 64) return;

    const float c    = 0.5f * xmax;
    const float Tcap = c - 0.0055f;
    const int   nn   = ovf ? 0 : cnt;
    float T = c - 1.0f;

    for (int it = 0; it < NEWTON_IT; ++it) {
        float S1 = 0.f, S2 = 0.f;
        for (int j = lane; j < nn; j += 64) {
            float u = fmaxf(s_buf[j] - T, 0.f);
            S1 += u; S2 = fmaf(u, u, S2);
        }
        if (ovf)
            for (int j = lane; j < D; j += 64) {
                float u = fmaxf(0.5f * row[j] - T, 0.f);
                S1 += u; S2 = fmaf(u, u, S2);
            }
#pragma unroll
        for (int off = 32; off > 0; off >>= 1) {
            S1 += __shfl_xor(S1, off);
            S2 += __shfl_xor(S2, off);
        }
        T = fminf(T + 0.5f * (S2 - 1.0f) / S1, Tcap);
    }
    {
        float k = 0.f, B = 0.f, A = 0.f;
        for (int j = lane; j < nn; j += 64) {
            float y = s_buf[j];
            if (y > T) { k += 1.f; B += y; A = fmaf(y, y, A); }
        }
        if (ovf)
            for (int j = lane; j < D; j += 64) {
                float y = 0.5f * row[j];
                if (y > T) { k += 1.f; B += y; A = fmaf(y, y, A); }
            }
#pragma unroll
        for (int off = 32; off > 0; off >>= 1) {
            k += __shfl_xor(k, off);
            B += __shfl_xor(B, off);
            A += __shfl_xor(A, off);
        }
        float mean  = B / k;
        float delta = fmaxf(fmaf(mean, mean, -(A - 1.f) / k), 0.f);
        T = fminf(mean - sqrtf(delta), Tcap);
    }
    float S15 = 0.f, Spx = 0.f;
    for (int j = lane; j < nn; j += 64) {
        float y = s_buf[j];
        float u = y - T;
        if (u > 0.f) { float p = u * u; S15 = fmaf(p, u, S15); Spx = fmaf(p, 2.f * y, Spx); }
    }
    if (ovf)
        for (int j = lane; j < D; j += 64) {
            float xv = row[j];
            float u  = 0.5f * xv - T;
            if (u > 0.f) { float p = u * u; S15 = fmaf(p, u, S15); Spx = fmaf(p, xv, Spx); }
        }
#pragma unroll
    for (int off = 32; off > 0; off >>= 1) {
        S15 += __shfl_xor(S15, off);
        Spx += __shfl_xor(Spx, off);
    }
    if (lane == 0) {
        float xt   = row[tgt[r]];
        float loss = (1.f - S15) * (4.f / 3.f) + Spx - xt;
        atomicAdd(out, loss * inv_n);
    }
}

extern "C" void kernel_launch(void* const* d_in, const int* in_sizes, int n_in,
                              void* d_out, int out_size, void* d_ws, size_t ws_size,
                              hipStream_t stream) {
    const float* xin = (const float*)d_in[0];
    const int*   tgt = (const int*)d_in[1];
    float*       out = (float*)d_out;
    const int n = in_sizes[0] / D;           // 4096 rows
    const float inv_n = 1.0f / (float)n;

    // ws layout (floats): [0,n) partial | [n,2n) maxs | [2n,3n) cnts(int)
    //                     | [coff, coff + n*CAPF) candidates
    const size_t coff = ((size_t)3 * n + 63) & ~(size_t)63;
    const size_t need = (coff + (size_t)n * CAPF) * sizeof(float);

    if (d_ws && ws_size >= need) {
        float* wsf     = (float*)d_ws;
        float* partial = wsf;
        float* maxs    = wsf + n;
        int*   cnts    = (int*)(wsf + 2 * (size_t)n);
        float* cand    = wsf + coff;

        entmax15_collect<<<n, BLK, 0, stream>>>(xin, maxs, cnts, cand);
        entmax15_solve<<<n, 64, 0, stream>>>(xin, tgt, maxs, cnts, cand, partial);
        reduce_partials<<<1, 1024, 0, stream>>>(partial, out, n, inv_n);
    } else {
        hipMemsetAsync(out, 0, sizeof(float), stream);
        entmax15_rows<<<n, BLK, 0, stream>>>(xin, tgt, out, inv_n);
    }
}